// Round 7
// baseline (354.809 us; speedup 1.0000x reference)
//
#include <hip/hip_runtime.h>
#include <hip/hip_bf16.h>
#include <hip/hip_fp16.h>

// ---------------- problem constants ----------------
namespace {
constexpr int kB = 1, kT = 2, kV = 3;
constexpr int kGH = 32, kGW = 64;
constexpr int kNG = kV * kGH * kGW;      // 6144 gaussians per (b,t)
constexpr int kNBT = kB * kT;            // 2
constexpr int kNI = kNBT * kV;           // 6 render instances
constexpr int kH = 224, kW = 448;
constexpr int kHW = kH * kW;             // 100352

// tile rasterizer: 16x4 pixels per 64-thread (1-wave) WG, 5x5 footprint
constexpr int kTX = 16, kTY = 4;
constexpr int kTilesX = kW / kTX;        // 28
constexpr int kTilesY = kH / kTY;        // 56
constexpr int kNTiles = kTilesX * kTilesY; // 1568
constexpr int kNBins = kNI * kNTiles;    // 9408
constexpr int kCAP = 256;                // per-tile capacity (hot est ~110 at this window)
constexpr int kMaxEnt = kNI * kNG;       // 36864 (< 65536 -> u16 ids)

// output bases (floats)
constexpr size_t RGB_SZ = (size_t)kNI * 3 * kHW;
constexpr size_t A_SZ   = (size_t)kNI * kHW;
constexpr size_t O_RGB_STA = 0;
constexpr size_t O_RGB_DYN = O_RGB_STA + RGB_SZ;
constexpr size_t O_RGB_ALL = O_RGB_DYN + RGB_SZ;
constexpr size_t O_A_STA   = O_RGB_ALL + RGB_SZ;
constexpr size_t O_A_DYN   = O_A_STA + A_SZ;
constexpr size_t O_A_ALL   = O_A_DYN + A_SZ;
constexpr size_t O_SEM     = O_A_ALL + A_SZ;
constexpr size_t O_SM      = O_SEM + A_SZ;
constexpr size_t O_TR      = O_SM + 1;

// workspace layout (bytes), total ~6.3 MB
constexpr size_t WS_CNTR  = 512;   // entCnt @+0, sigmaSum[6] @+16, cnt[6] @+48, touch[6] @+80, done @+112
constexpr size_t WS_TCNT  = 1024;                                   // int[kNBins] = 37632 B
constexpr size_t WS_TLIST = WS_TCNT + (size_t)kNBins * 4;           // u16[kNBins*kCAP] = 4,816,896 B
constexpr size_t WS_PAY   = WS_TLIST + (size_t)kNBins * kCAP * 2;   // f32[12*kMaxEnt] = 1,769,472 B

__device__ __forceinline__ float clip01(float x) { return fminf(fmaxf(x, 0.f), 1.f); }
__device__ __forceinline__ unsigned long long packkey(int zbits, int ikey) {
    return ((unsigned long long)(unsigned)zbits << 32) | (unsigned)ikey;
}
__device__ __forceinline__ float packh2(float a, float b) {
    __half2 h = __floats2half2_rn(a, b);
    return __uint_as_float(*reinterpret_cast<unsigned*>(&h));
}
__device__ __forceinline__ float2 unpackh2(float f) {
    unsigned u = __float_as_uint(f);
    return __half22float2(*reinterpret_cast<__half2*>(&u));
}
}

// ---------------- kernels ----------------

// project, emit payloads, append entry ids into per-tile bins; 4x4 inverse inlined
__global__ void k_pre(const float* __restrict__ centers, const float* __restrict__ scale,
                      const float* __restrict__ feat, const float* __restrict__ opac,
                      const float* __restrict__ bgp, const float* __restrict__ intr,
                      const float* __restrict__ fpose, const float* __restrict__ c2w,
                      int* __restrict__ entCnt, float* __restrict__ sigmaSum, int* __restrict__ cnt,
                      int* __restrict__ tileCnt, unsigned short* __restrict__ tileList,
                      float* __restrict__ pay) {
    __shared__ float sW[16];
    int inst = blockIdx.y;
    // thread 0: Gauss-Jordan inverse of c2w[inst] (redundant per WG, negligible)
    if (threadIdx.x == 0) {
        float m[4][8];
        const float* A = c2w + (size_t)inst * 16;
        for (int r = 0; r < 4; ++r)
            for (int cc = 0; cc < 4; ++cc) { m[r][cc] = A[r * 4 + cc]; m[r][cc + 4] = (r == cc) ? 1.f : 0.f; }
        for (int col = 0; col < 4; ++col) {
            int piv = col; float mx = fabsf(m[col][col]);
            for (int r = col + 1; r < 4; ++r) { float a = fabsf(m[r][col]); if (a > mx) { mx = a; piv = r; } }
            if (piv != col)
                for (int cc = 0; cc < 8; ++cc) { float tt = m[col][cc]; m[col][cc] = m[piv][cc]; m[piv][cc] = tt; }
            float inv = 1.f / m[col][col];
            for (int cc = 0; cc < 8; ++cc) m[col][cc] *= inv;
            for (int r = 0; r < 4; ++r) {
                if (r == col) continue;
                float f = m[r][col];
                for (int cc = 0; cc < 8; ++cc) m[r][cc] -= f * m[col][cc];
            }
        }
        for (int r = 0; r < 4; ++r)
            for (int cc = 0; cc < 4; ++cc) sW[r * 4 + cc] = m[r][cc + 4];
    }
    __syncthreads();

    int g = blockIdx.x * 256 + threadIdx.x;   // grid exact: 6144 = 24*256
    int bt = inst / kV, v = inst % kV;
    int b = bt / kT;

    const float* c = centers + ((size_t)bt * kNG + g) * 3;
    float c0 = c[0], c1 = c[1], c2 = c[2];
    const float* P = fpose + (size_t)b * 16;
    float wx[4];
#pragma unroll
    for (int i = 0; i < 4; ++i)
        wx[i] = P[i * 4 + 0] * c0 + P[i * 4 + 1] * c1 + P[i * 4 + 2] * c2 + P[i * 4 + 3];

    float camx = sW[0] * wx[0] + sW[1] * wx[1] + sW[2] * wx[2] + sW[3] * wx[3];
    float camy = sW[4] * wx[0] + sW[5] * wx[1] + sW[6] * wx[2] + sW[7] * wx[3];
    float camz = sW[8] * wx[0] + sW[9] * wx[1] + sW[10] * wx[2] + sW[11] * wx[3];

    float op = clip01(opac[(size_t)bt * kNG + g]);
    bool zok = (camz > 0.001f) && isfinite(camx) && isfinite(camy) && isfinite(camz);
    bool valid0 = zok && (op > 1e-5f);

    const float* it = intr + ((size_t)b * kV + v) * 4;
    float fx = it[0], fy = it[1], cx = it[2], cy = it[3];
    float u = camx * fx / camz + cx;
    float vv = camy * fy / camz + cy;

    const float* sp = scale + ((size_t)bt * kNG + g) * 3;
    float sf = (sp[0] + sp[1] + sp[2]) / 3.f;
    float sg = fminf(fmaxf((fx + fy) * 0.5f * fabsf(sf) / fmaxf(camz, 0.001f), 0.75f), 10.f);

    bool inb = (u >= -3.f) && (u <= (float)kW + 2.f) && (vv >= -3.f) && (vv <= (float)kH + 2.f);
    bool statsValid = valid0 && inb;

    // wave-reduced sigma/cnt stats (1 atomic pair per wave)
    float ssum = statsValid ? sg : 0.f;
    int scnt = statsValid ? 1 : 0;
#pragma unroll
    for (int o = 32; o > 0; o >>= 1) {
        ssum += __shfl_down(ssum, o);
        scnt += __shfl_down(scnt, o);
    }
    if ((threadIdx.x & 63) == 0 && scnt > 0) {
        atomicAdd(&sigmaSum[inst], ssum);
        atomicAdd(&cnt[inst], scnt);
    }

    int x0 = (int)floorf(u);
    int y0 = (int)floorf(vv);
    bool emit = statsValid && (x0 >= -2) && (x0 <= kW + 1) && (y0 >= -2) && (y0 <= kH + 1);
    if (!emit) return;

    float bg = bgp[(size_t)bt * kNG + g];
    float dyn = clip01(1.f - bg);
    float aAll = op;
    float aDyn = clip01(op * dyn);
    float aSta = clip01(op * (1.f - dyn));
    if (aDyn <= 1e-5f) aDyn = 0.f;
    if (aSta <= 1e-5f) aSta = 0.f;

    const float* fc = feat + ((size_t)bt * kNG + g) * 3;
    float r = clip01(fc[0]), gc = clip01(fc[1]), bcl = clip01(fc[2]);

    int e = atomicAdd(entCnt, 1);
    float4* p4 = (float4*)(pay + (size_t)e * 12);
    int keybits = (g << 16) | e;
    p4[0] = make_float4(u, vv, 1.f / fmaxf(sg, 0.001f), aSta);
    p4[1] = make_float4(aDyn, aAll, r, gc);
    p4[2] = make_float4(bcl, camz, __int_as_float(keybits), 0.f);

    // overlapping 16x4 tiles: pixels [x0-2,x0+2]x[y0-2,y0+2]
    int ilo = x0 - 2 < 0 ? 0 : (x0 - 2) / kTX;
    int ihi = min(kTilesX - 1, (x0 + 2) / kTX);
    int jlo = y0 - 2 < 0 ? 0 : (y0 - 2) / kTY;
    int jhi = min(kTilesY - 1, (y0 + 2) / kTY);
    for (int j = jlo; j <= jhi; ++j)
        for (int i = ilo; i <= ihi; ++i) {
            int bin = inst * kNTiles + j * kTilesX + i;
            int idx = atomicAdd(&tileCnt[bin], 1);
            if (idx < kCAP) tileList[(size_t)bin * kCAP + idx] = (unsigned short)e;
        }
}

// tiled rasterizer: 1 wave per 16x4 tile; gather+rank-sort, branch-free unroll-4 composite
__global__ __launch_bounds__(64) void k_tile(const int* __restrict__ tileCnt,
                                             const unsigned short* __restrict__ tileList,
                                             const float* __restrict__ pay,
                                             const float* __restrict__ sem,
                                             const float* __restrict__ sigmaSum,
                                             const int* __restrict__ cnt,
                                             float* __restrict__ out,
                                             int* __restrict__ touch,
                                             int* __restrict__ done) {
    __shared__ float4 shA[kCAP];
    __shared__ float2 shB[kCAP];
    __shared__ unsigned long long shKey[kCAP];

    int t = threadIdx.x;
    int tile = blockIdx.x;
    int inst = blockIdx.y;
    int bin = inst * kNTiles + tile;
    int N = tileCnt[bin];
    if (N > kCAP) N = kCAP;

    // gather 4 slots per thread (kCAP = 4*64), records stay in registers until rank known
    unsigned long long k0 = ~0ULL, k1 = ~0ULL, k2 = ~0ULL, k3 = ~0ULL;
    float4 a0, a1, a2, a3; float2 b0, b1, b2, b3;
#define GATHER(q, kq, aq, bq)                                              \
    {   int i = t + 64 * q;                                                \
        if (i < N) {                                                       \
            int e = tileList[(size_t)bin * kCAP + i];                      \
            const float4* pp = (const float4*)(pay + (size_t)e * 12);      \
            float4 p0 = pp[0], p1 = pp[1], p2 = pp[2];                     \
            kq = packkey(__float_as_int(p2.y), __float_as_int(p2.z));      \
            shKey[i] = kq;                                                 \
            aq = make_float4(p0.x, p0.y, p0.z, packh2(p0.w, p1.x));        \
            bq = make_float2(packh2(p1.y, p1.z), packh2(p1.w, p2.x));      \
        } }
    GATHER(0, k0, a0, b0) GATHER(1, k1, a1, b1) GATHER(2, k2, a2, b2) GATHER(3, k3, a3, b3)
#undef GATHER
    __syncthreads();

    // rank sort (keys unique: low bits hold entry id)
    int r0i = 0, r1i = 0, r2i = 0, r3i = 0;
    for (int j = 0; j < N; ++j) {
        unsigned long long kj = shKey[j];
        r0i += (kj < k0); r1i += (kj < k1); r2i += (kj < k2); r3i += (kj < k3);
    }
    __syncthreads();
    if (t < N)        { shA[r0i] = a0; shB[r0i] = b0; }
    if (t + 64 < N)   { shA[r1i] = a1; shB[r1i] = b1; }
    if (t + 128 < N)  { shA[r2i] = a2; shB[r2i] = b2; }
    if (t + 192 < N)  { shA[r3i] = a3; shB[r3i] = b3; }
    int Npad = (N + 3) & ~3;
    if (t < Npad - N) {
        shA[N + t] = make_float4(0.f, 0.f, 0.f, 0.f);
        shB[N + t] = make_float2(0.f, 0.f);
    }
    __syncthreads();

    // composite: one pixel per lane, branch-free unroll-4
    int tx = (tile % kTilesX) * kTX;
    int ty = (tile / kTilesX) * kTY;
    int px = tx + (t & (kTX - 1));
    int py = ty + (t >> 4);
    float fpx = (float)px, fpy = (float)py;

    float ad0 = 0.f, ad1 = 0.f, ad2 = 0.f;
    float sr0 = 0.f, sg0 = 0.f, sb0 = 0.f;
    float sr1 = 0.f, sg1 = 0.f, sb1 = 0.f;
    float sr2 = 0.f, sg2 = 0.f, sb2 = 0.f;

#define COMP(aq, bq)                                                        \
    {   float dxc = fpx - floorf(aq.x);                                     \
        float dyc = fpy - floorf(aq.y);                                     \
        bool keep = (dxc >= -2.f) && (dxc <= 2.f) && (dyc >= -2.f) && (dyc <= 2.f); \
        float du = (aq.x - fpx) * aq.z;                                     \
        float dv = (aq.y - fpy) * aq.z;                                     \
        float lb = expf(-0.5f * (du * du + dv * dv));                       \
        lb = keep ? lb : 0.f;                                               \
        float2 sd = unpackh2(aq.w);   /* aSta, aDyn */                      \
        float2 ar = unpackh2(bq.x);   /* aAll, r */                         \
        float2 gb = unpackh2(bq.y);   /* g, b */                            \
        float la, Tt, ct;                                                   \
        la = fminf(lb * sd.x, 0.999f);                                      \
        Tt = clip01(1.f - ad0); ct = la * Tt;                               \
        ad0 = fminf(ad0 + ct, 0.999f);                                      \
        sr0 += ar.y * ct; sg0 += gb.x * ct; sb0 += gb.y * ct;               \
        la = fminf(lb * sd.y, 0.999f);                                      \
        Tt = clip01(1.f - ad1); ct = la * Tt;                               \
        ad1 = fminf(ad1 + ct, 0.999f);                                      \
        sr1 += ar.y * ct; sg1 += gb.x * ct; sb1 += gb.y * ct;               \
        la = fminf(lb * ar.x, 0.999f);                                      \
        Tt = clip01(1.f - ad2); ct = la * Tt;                               \
        ad2 = fminf(ad2 + ct, 0.999f);                                      \
        sr2 += ar.y * ct; sg2 += gb.x * ct; sb2 += gb.y * ct;               \
    }

    for (int k = 0; k < Npad; k += 4) {
        float4 qa0 = shA[k + 0], qa1 = shA[k + 1], qa2 = shA[k + 2], qa3 = shA[k + 3];
        float2 qb0 = shB[k + 0], qb1 = shB[k + 1], qb2 = shB[k + 2], qb3 = shB[k + 3];
        COMP(qa0, qb0) COMP(qa1, qb1) COMP(qa2, qb2) COMP(qa3, qb3)
    }
#undef COMP

    unsigned long long tm = __ballot(ad2 > 1e-6f);
    if (t == 0 && tm) atomicAdd(&touch[inst], __popcll(tm));

    size_t o = (size_t)py * kW + px;
    size_t ib3 = (size_t)inst * 3;
    out[O_RGB_STA + (ib3 + 0) * kHW + o] = clip01(sr0);
    out[O_RGB_STA + (ib3 + 1) * kHW + o] = clip01(sg0);
    out[O_RGB_STA + (ib3 + 2) * kHW + o] = clip01(sb0);
    out[O_RGB_DYN + (ib3 + 0) * kHW + o] = clip01(sr1);
    out[O_RGB_DYN + (ib3 + 1) * kHW + o] = clip01(sg1);
    out[O_RGB_DYN + (ib3 + 2) * kHW + o] = clip01(sb1);
    out[O_RGB_ALL + (ib3 + 0) * kHW + o] = clip01(sr2);
    out[O_RGB_ALL + (ib3 + 1) * kHW + o] = clip01(sg2);
    out[O_RGB_ALL + (ib3 + 2) * kHW + o] = clip01(sb2);
    out[O_A_STA + (size_t)inst * kHW + o] = ad0;
    out[O_A_DYN + (size_t)inst * kHW + o] = ad1;
    out[O_A_ALL + (size_t)inst * kHW + o] = ad2;
    out[O_SEM + (size_t)inst * kHW + o] = sem[(size_t)inst * kHW + o];

    // last-WG finalize (replaces k_fin dispatch)
    __threadfence();
    if (t == 0) {
        int old = atomicAdd(done, 1);
        if (old == kNBins - 1) {
            __threadfence();
            float sm = 0.f, tr = 0.f;
            for (int i = 0; i < kNI; ++i) {
                float ss = atomicAdd((float*)&sigmaSum[i], 0.f);
                int cc = atomicAdd((int*)&cnt[i], 0);
                int tc = atomicAdd(&touch[i], 0);
                sm += ss / fmaxf((float)cc, 1.f);
                tr += (float)tc / (float)kHW;
            }
            out[O_SM] = sm / (float)kNI;
            out[O_TR] = tr / (float)kNI;
        }
    }
}

// ---------------- launch ----------------
extern "C" void kernel_launch(void* const* d_in, const int* in_sizes, int n_in,
                              void* d_out, int out_size, void* d_ws, size_t ws_size,
                              hipStream_t stream) {
    const float* centers = (const float*)d_in[0];
    const float* scal    = (const float*)d_in[1];
    const float* feat    = (const float*)d_in[2];
    const float* opac    = (const float*)d_in[3];
    const float* bgp     = (const float*)d_in[4];
    const float* sem     = (const float*)d_in[5];
    const float* intr    = (const float*)d_in[6];
    const float* c2w     = (const float*)d_in[7];
    const float* fpose   = (const float*)d_in[8];
    float* out = (float*)d_out;
    char* ws = (char*)d_ws;

    int*   entCnt   = (int*)(ws + WS_CNTR);
    float* sigmaSum = (float*)(ws + WS_CNTR + 16);
    int*   cnt      = (int*)(ws + WS_CNTR + 48);
    int*   touch    = (int*)(ws + WS_CNTR + 80);
    int*   done     = (int*)(ws + WS_CNTR + 112);
    int*   tileCnt  = (int*)(ws + WS_TCNT);
    unsigned short* tileList = (unsigned short*)(ws + WS_TLIST);
    float* pay      = (float*)(ws + WS_PAY);

    // zero counters + tile counts (512 .. WS_TLIST)
    hipMemsetAsync(ws + WS_CNTR, 0, WS_TLIST - WS_CNTR, stream);

    dim3 gpre(kNG / 256, kNI);
    k_pre<<<gpre, 256, 0, stream>>>(centers, scal, feat, opac, bgp, intr, fpose, c2w,
                                    entCnt, sigmaSum, cnt, tileCnt, tileList, pay);

    dim3 gtile(kNTiles, kNI);
    k_tile<<<gtile, 64, 0, stream>>>(tileCnt, tileList, pay, sem, sigmaSum, cnt,
                                     out, touch, done);
}

// Round 8
// 147.776 us; speedup vs baseline: 2.4010x; 2.4010x over previous
//
#include <hip/hip_runtime.h>
#include <hip/hip_bf16.h>
#include <hip/hip_fp16.h>

// ---------------- problem constants ----------------
namespace {
constexpr int kB = 1, kT = 2, kV = 3;
constexpr int kGH = 32, kGW = 64;
constexpr int kNG = kV * kGH * kGW;      // 6144 gaussians per (b,t)
constexpr int kNBT = kB * kT;            // 2
constexpr int kNI = kNBT * kV;           // 6 render instances
constexpr int kH = 224, kW = 448;
constexpr int kHW = kH * kW;             // 100352

// tile rasterizer: 32x8 pixels per 256-thread WG, 5x5 footprint
constexpr int kTX = 32, kTY = 8;
constexpr int kTilesX = kW / kTX;        // 14
constexpr int kTilesY = kH / kTY;        // 28
constexpr int kNTiles = kTilesX * kTilesY; // 392
constexpr int kNBins = kNI * kNTiles;    // 2352
constexpr int kCAP = 512;                // per-tile capacity (never hit: r5/r6 verified)
constexpr int kMaxEnt = kNI * kNG;       // 36864 (< 65536 -> u16 ids)

// output bases (floats)
constexpr size_t RGB_SZ = (size_t)kNI * 3 * kHW;
constexpr size_t A_SZ   = (size_t)kNI * kHW;
constexpr size_t O_RGB_STA = 0;
constexpr size_t O_RGB_DYN = O_RGB_STA + RGB_SZ;
constexpr size_t O_RGB_ALL = O_RGB_DYN + RGB_SZ;
constexpr size_t O_A_STA   = O_RGB_ALL + RGB_SZ;
constexpr size_t O_A_DYN   = O_A_STA + A_SZ;
constexpr size_t O_A_ALL   = O_A_DYN + A_SZ;
constexpr size_t O_SEM     = O_A_ALL + A_SZ;
constexpr size_t O_SM      = O_SEM + A_SZ;
constexpr size_t O_TR      = O_SM + 1;

// workspace layout (bytes), total ~4.2 MB
constexpr size_t WS_CNTR  = 512;   // entCnt @+0, sigmaSum[6] @+16, cnt[6] @+48, touch[6] @+80
constexpr size_t WS_TCNT  = 1024;                                   // int[kNBins] = 9408 B
constexpr size_t WS_TLIST = WS_TCNT + (size_t)kNBins * 4;           // u16[kNBins*kCAP] = 2,408,448 B
constexpr size_t WS_PAY   = WS_TLIST + (size_t)kNBins * kCAP * 2;   // f32[12*kMaxEnt] = 1,769,472 B

__device__ __forceinline__ float clip01(float x) { return fminf(fmaxf(x, 0.f), 1.f); }
__device__ __forceinline__ unsigned long long packkey(int zbits, int ikey) {
    return ((unsigned long long)(unsigned)zbits << 32) | (unsigned)ikey;
}
__device__ __forceinline__ float packh2(float a, float b) {
    __half2 h = __floats2half2_rn(a, b);
    return __uint_as_float(*reinterpret_cast<unsigned*>(&h));
}
__device__ __forceinline__ float2 unpackh2(float f) {
    unsigned u = __float_as_uint(f);
    return __half22float2(*reinterpret_cast<__half2*>(&u));
}
}

// ---------------- kernels ----------------

// project, emit payloads, append entry ids into per-tile bins; 4x4 inverse inlined
__global__ void k_pre(const float* __restrict__ centers, const float* __restrict__ scale,
                      const float* __restrict__ feat, const float* __restrict__ opac,
                      const float* __restrict__ bgp, const float* __restrict__ intr,
                      const float* __restrict__ fpose, const float* __restrict__ c2w,
                      int* __restrict__ entCnt, float* __restrict__ sigmaSum, int* __restrict__ cnt,
                      int* __restrict__ tileCnt, unsigned short* __restrict__ tileList,
                      float* __restrict__ pay) {
    __shared__ float sW[16];
    int inst = blockIdx.y;
    if (threadIdx.x == 0) {   // Gauss-Jordan inverse of c2w[inst]
        float m[4][8];
        const float* A = c2w + (size_t)inst * 16;
        for (int r = 0; r < 4; ++r)
            for (int cc = 0; cc < 4; ++cc) { m[r][cc] = A[r * 4 + cc]; m[r][cc + 4] = (r == cc) ? 1.f : 0.f; }
        for (int col = 0; col < 4; ++col) {
            int piv = col; float mx = fabsf(m[col][col]);
            for (int r = col + 1; r < 4; ++r) { float a = fabsf(m[r][col]); if (a > mx) { mx = a; piv = r; } }
            if (piv != col)
                for (int cc = 0; cc < 8; ++cc) { float tt = m[col][cc]; m[col][cc] = m[piv][cc]; m[piv][cc] = tt; }
            float inv = 1.f / m[col][col];
            for (int cc = 0; cc < 8; ++cc) m[col][cc] *= inv;
            for (int r = 0; r < 4; ++r) {
                if (r == col) continue;
                float f = m[r][col];
                for (int cc = 0; cc < 8; ++cc) m[r][cc] -= f * m[col][cc];
            }
        }
        for (int r = 0; r < 4; ++r)
            for (int cc = 0; cc < 4; ++cc) sW[r * 4 + cc] = m[r][cc + 4];
    }
    __syncthreads();

    int g = blockIdx.x * 256 + threadIdx.x;   // grid exact: 6144 = 24*256
    int bt = inst / kV, v = inst % kV;
    int b = bt / kT;

    const float* c = centers + ((size_t)bt * kNG + g) * 3;
    float c0 = c[0], c1 = c[1], c2 = c[2];
    const float* P = fpose + (size_t)b * 16;
    float wx[4];
#pragma unroll
    for (int i = 0; i < 4; ++i)
        wx[i] = P[i * 4 + 0] * c0 + P[i * 4 + 1] * c1 + P[i * 4 + 2] * c2 + P[i * 4 + 3];

    float camx = sW[0] * wx[0] + sW[1] * wx[1] + sW[2] * wx[2] + sW[3] * wx[3];
    float camy = sW[4] * wx[0] + sW[5] * wx[1] + sW[6] * wx[2] + sW[7] * wx[3];
    float camz = sW[8] * wx[0] + sW[9] * wx[1] + sW[10] * wx[2] + sW[11] * wx[3];

    float op = clip01(opac[(size_t)bt * kNG + g]);
    bool zok = (camz > 0.001f) && isfinite(camx) && isfinite(camy) && isfinite(camz);
    bool valid0 = zok && (op > 1e-5f);

    const float* it = intr + ((size_t)b * kV + v) * 4;
    float fx = it[0], fy = it[1], cx = it[2], cy = it[3];
    float u = camx * fx / camz + cx;
    float vv = camy * fy / camz + cy;

    const float* sp = scale + ((size_t)bt * kNG + g) * 3;
    float sf = (sp[0] + sp[1] + sp[2]) / 3.f;
    float sg = fminf(fmaxf((fx + fy) * 0.5f * fabsf(sf) / fmaxf(camz, 0.001f), 0.75f), 10.f);

    bool inb = (u >= -3.f) && (u <= (float)kW + 2.f) && (vv >= -3.f) && (vv <= (float)kH + 2.f);
    bool statsValid = valid0 && inb;

    // wave-reduced sigma/cnt stats (1 atomic pair per wave)
    float ssum = statsValid ? sg : 0.f;
    int scnt = statsValid ? 1 : 0;
#pragma unroll
    for (int o = 32; o > 0; o >>= 1) {
        ssum += __shfl_down(ssum, o);
        scnt += __shfl_down(scnt, o);
    }
    if ((threadIdx.x & 63) == 0 && scnt > 0) {
        atomicAdd(&sigmaSum[inst], ssum);
        atomicAdd(&cnt[inst], scnt);
    }

    int x0 = (int)floorf(u);
    int y0 = (int)floorf(vv);
    bool emit = statsValid && (x0 >= -2) && (x0 <= kW + 1) && (y0 >= -2) && (y0 <= kH + 1);
    if (!emit) return;

    float bg = bgp[(size_t)bt * kNG + g];
    float dyn = clip01(1.f - bg);
    float aAll = op;
    float aDyn = clip01(op * dyn);
    float aSta = clip01(op * (1.f - dyn));
    if (aDyn <= 1e-5f) aDyn = 0.f;
    if (aSta <= 1e-5f) aSta = 0.f;

    const float* fc = feat + ((size_t)bt * kNG + g) * 3;
    float r = clip01(fc[0]), gc = clip01(fc[1]), bcl = clip01(fc[2]);

    int e = atomicAdd(entCnt, 1);
    float4* p4 = (float4*)(pay + (size_t)e * 12);
    int keybits = (g << 16) | e;
    p4[0] = make_float4(u, vv, 1.f / fmaxf(sg, 0.001f), aSta);
    p4[1] = make_float4(aDyn, aAll, r, gc);
    p4[2] = make_float4(bcl, camz, __int_as_float(keybits), 0.f);

    // overlapping 32x8 tiles of the footprint [x0-2,x0+2]x[y0-2,y0+2]
    int ilo = x0 - 2 < 0 ? 0 : (x0 - 2) / kTX;
    int ihi = min(kTilesX - 1, (x0 + 2) / kTX);
    int jlo = y0 - 2 < 0 ? 0 : (y0 - 2) / kTY;
    int jhi = min(kTilesY - 1, (y0 + 2) / kTY);
    for (int j = jlo; j <= jhi; ++j)
        for (int i = ilo; i <= ihi; ++i) {
            int bin = inst * kNTiles + j * kTilesX + i;
            int idx = atomicAdd(&tileCnt[bin], 1);
            if (idx < kCAP) tileList[(size_t)bin * kCAP + idx] = (unsigned short)e;
        }
}

// tiled rasterizer: gather own bin, rank-sort by (z,g), pipelined branch-free composite
__global__ __launch_bounds__(256) void k_tile(const int* __restrict__ tileCnt,
                                              const unsigned short* __restrict__ tileList,
                                              const float* __restrict__ pay,
                                              float* __restrict__ out,
                                              int* __restrict__ touch) {
    __shared__ unsigned long long shKey[kCAP];
    __shared__ float4 shA[kCAP + 8];
    __shared__ float2 shB[kCAP + 8];

    int t = threadIdx.x;
    int tile = blockIdx.x;
    int inst = blockIdx.y;
    int bin = inst * kNTiles + tile;
    int N = tileCnt[bin];
    if (N > kCAP) N = kCAP;

    // gather 2 slots per thread (kCAP = 2*256); records in registers until rank known
    unsigned long long kA = ~0ULL, kB = ~0ULL;
    float4 aA, aB; float2 bA, bB;
#define GATHER(i, kq, aq, bq)                                              \
    {   if (i < N) {                                                       \
            int e = tileList[(size_t)bin * kCAP + i];                      \
            const float4* pp = (const float4*)(pay + (size_t)e * 12);      \
            float4 p0 = pp[0], p1 = pp[1], p2 = pp[2];                     \
            kq = packkey(__float_as_int(p2.y), __float_as_int(p2.z));      \
            shKey[i] = kq;                                                 \
            aq = make_float4(p0.x, p0.y, p0.z, packh2(p0.w, p1.x));        \
            bq = make_float2(packh2(p1.y, p1.z), packh2(p1.w, p2.x));      \
        } }
    GATHER(t, kA, aA, bA)
    GATHER(t + 256, kB, aB, bB)
#undef GATHER
    __syncthreads();

    // rank sort (keys unique: low bits hold entry id)
    int rA = 0, rB = 0;
    for (int j = 0; j < N; ++j) {
        unsigned long long kj = shKey[j];
        rA += (kj < kA); rB += (kj < kB);
    }
    __syncthreads();
    if (t < N)       { shA[rA] = aA; shB[rA] = bA; }
    if (t + 256 < N) { shA[rB] = aB; shB[rB] = bB; }
    if (t < 8) {   // zero padding slots for the prefetch pipeline (no-op records)
        shA[N + t] = make_float4(0.f, 0.f, 0.f, 0.f);
        shB[N + t] = make_float2(0.f, 0.f);
    }
    __syncthreads();

    // composite: one pixel per thread, software-pipelined (prefetch k+1 while compositing k)
    int tx = (tile % kTilesX) * kTX;
    int ty = (tile / kTilesX) * kTY;
    int px = tx + (t & (kTX - 1));
    int py = ty + (t >> 5);
    float fpx = (float)px, fpy = (float)py;

    float ad0 = 0.f, ad1 = 0.f, ad2 = 0.f;
    float sr0 = 0.f, sg0 = 0.f, sb0 = 0.f;
    float sr1 = 0.f, sg1 = 0.f, sb1 = 0.f;
    float sr2 = 0.f, sg2 = 0.f, sb2 = 0.f;

    float4 Ac = shA[0]; float2 Bc = shB[0];
    for (int k = 0; k < N; ++k) {
        float4 An = shA[k + 1]; float2 Bn = shB[k + 1];   // prefetch next (pad-safe)
        {
            float dxc = fpx - floorf(Ac.x);
            float dyc = fpy - floorf(Ac.y);
            bool keep = (dxc >= -2.f) && (dxc <= 2.f) && (dyc >= -2.f) && (dyc <= 2.f);
            float du = (Ac.x - fpx) * Ac.z;
            float dv = (Ac.y - fpy) * Ac.z;
            float lb = expf(-0.5f * (du * du + dv * dv));
            lb = keep ? lb : 0.f;
            float2 sd = unpackh2(Ac.w);   // aSta, aDyn
            float2 ar = unpackh2(Bc.x);   // aAll, r
            float2 gb = unpackh2(Bc.y);   // g, b
            float la, Tt, ct;
            la = fminf(lb * sd.x, 0.999f);
            Tt = clip01(1.f - ad0); ct = la * Tt;
            ad0 = fminf(ad0 + ct, 0.999f);
            sr0 += ar.y * ct; sg0 += gb.x * ct; sb0 += gb.y * ct;
            la = fminf(lb * sd.y, 0.999f);
            Tt = clip01(1.f - ad1); ct = la * Tt;
            ad1 = fminf(ad1 + ct, 0.999f);
            sr1 += ar.y * ct; sg1 += gb.x * ct; sb1 += gb.y * ct;
            la = fminf(lb * ar.x, 0.999f);
            Tt = clip01(1.f - ad2); ct = la * Tt;
            ad2 = fminf(ad2 + ct, 0.999f);
            sr2 += ar.y * ct; sg2 += gb.x * ct; sb2 += gb.y * ct;
        }
        Ac = An; Bc = Bn;
    }

    unsigned long long tm = __ballot(ad2 > 1e-6f);
    if ((t & 63) == 0 && tm) atomicAdd(&touch[inst], __popcll(tm));

    size_t o = (size_t)py * kW + px;
    size_t ib3 = (size_t)inst * 3;
    __builtin_nontemporal_store(clip01(sr0), &out[O_RGB_STA + (ib3 + 0) * kHW + o]);
    __builtin_nontemporal_store(clip01(sg0), &out[O_RGB_STA + (ib3 + 1) * kHW + o]);
    __builtin_nontemporal_store(clip01(sb0), &out[O_RGB_STA + (ib3 + 2) * kHW + o]);
    __builtin_nontemporal_store(clip01(sr1), &out[O_RGB_DYN + (ib3 + 0) * kHW + o]);
    __builtin_nontemporal_store(clip01(sg1), &out[O_RGB_DYN + (ib3 + 1) * kHW + o]);
    __builtin_nontemporal_store(clip01(sb1), &out[O_RGB_DYN + (ib3 + 2) * kHW + o]);
    __builtin_nontemporal_store(clip01(sr2), &out[O_RGB_ALL + (ib3 + 0) * kHW + o]);
    __builtin_nontemporal_store(clip01(sg2), &out[O_RGB_ALL + (ib3 + 1) * kHW + o]);
    __builtin_nontemporal_store(clip01(sb2), &out[O_RGB_ALL + (ib3 + 2) * kHW + o]);
    __builtin_nontemporal_store(ad0, &out[O_A_STA + (size_t)inst * kHW + o]);
    __builtin_nontemporal_store(ad1, &out[O_A_DYN + (size_t)inst * kHW + o]);
    __builtin_nontemporal_store(ad2, &out[O_A_ALL + (size_t)inst * kHW + o]);
}

__global__ void k_fin(const float* __restrict__ sigmaSum, const int* __restrict__ cnt,
                      const int* __restrict__ touch, float* __restrict__ out) {
    if (threadIdx.x == 0 && blockIdx.x == 0) {
        float sm = 0.f, tr = 0.f;
        for (int i = 0; i < kNI; ++i) {
            sm += sigmaSum[i] / fmaxf((float)cnt[i], 1.f);
            tr += (float)touch[i] / (float)kHW;
        }
        out[O_SM] = sm / (float)kNI;
        out[O_TR] = tr / (float)kNI;
    }
}

// ---------------- launch ----------------
extern "C" void kernel_launch(void* const* d_in, const int* in_sizes, int n_in,
                              void* d_out, int out_size, void* d_ws, size_t ws_size,
                              hipStream_t stream) {
    const float* centers = (const float*)d_in[0];
    const float* scal    = (const float*)d_in[1];
    const float* feat    = (const float*)d_in[2];
    const float* opac    = (const float*)d_in[3];
    const float* bgp     = (const float*)d_in[4];
    const float* sem     = (const float*)d_in[5];
    const float* intr    = (const float*)d_in[6];
    const float* c2w     = (const float*)d_in[7];
    const float* fpose   = (const float*)d_in[8];
    float* out = (float*)d_out;
    char* ws = (char*)d_ws;

    int*   entCnt   = (int*)(ws + WS_CNTR);
    float* sigmaSum = (float*)(ws + WS_CNTR + 16);
    int*   cnt      = (int*)(ws + WS_CNTR + 48);
    int*   touch    = (int*)(ws + WS_CNTR + 80);
    int*   tileCnt  = (int*)(ws + WS_TCNT);
    unsigned short* tileList = (unsigned short*)(ws + WS_TLIST);
    float* pay      = (float*)(ws + WS_PAY);

    // zero counters + tile counts
    hipMemsetAsync(ws + WS_CNTR, 0, WS_TLIST - WS_CNTR, stream);

    dim3 gpre(kNG / 256, kNI);
    k_pre<<<gpre, 256, 0, stream>>>(centers, scal, feat, opac, bgp, intr, fpose, c2w,
                                    entCnt, sigmaSum, cnt, tileCnt, tileList, pay);

    dim3 gtile(kNTiles, kNI);
    k_tile<<<gtile, 256, 0, stream>>>(tileCnt, tileList, pay, out, touch);

    hipMemcpyAsync(out + O_SEM, sem, (size_t)kNI * kHW * sizeof(float),
                   hipMemcpyDeviceToDevice, stream);

    k_fin<<<1, 1, 0, stream>>>(sigmaSum, cnt, touch, out);
}

// Round 9
// 85.097 us; speedup vs baseline: 4.1695x; 1.7366x over previous
//
#include <hip/hip_runtime.h>
#include <hip/hip_bf16.h>
#include <hip/hip_fp16.h>

// ---------------- problem constants ----------------
namespace {
constexpr int kB = 1, kT = 2, kV = 3;
constexpr int kGH = 32, kGW = 64;
constexpr int kNG = kV * kGH * kGW;      // 6144 gaussians per (b,t)
constexpr int kNBT = kB * kT;            // 2
constexpr int kNI = kNBT * kV;           // 6 render instances
constexpr int kH = 224, kW = 448;
constexpr int kHW = kH * kW;             // 100352

// tile rasterizer: 64x4 pixels per 256-thread WG, 5x5 footprint.
// Each wave = one 64-px row -> every per-plane store = 256B contiguous, 256B-aligned.
constexpr int kTX = 64, kTY = 4;
constexpr int kTilesX = kW / kTX;        // 7
constexpr int kTilesY = kH / kTY;        // 56
constexpr int kNTiles = kTilesX * kTilesY; // 392
constexpr int kNBins = kNI * kNTiles;    // 2352
constexpr int kCAP = 512;                // per-tile capacity (hot N ~95 est)
constexpr int kMaxEnt = kNI * kNG;       // 36864 (< 65536 -> u16 ids)

// output bases (floats)
constexpr size_t RGB_SZ = (size_t)kNI * 3 * kHW;
constexpr size_t A_SZ   = (size_t)kNI * kHW;
constexpr size_t O_RGB_STA = 0;
constexpr size_t O_RGB_DYN = O_RGB_STA + RGB_SZ;
constexpr size_t O_RGB_ALL = O_RGB_DYN + RGB_SZ;
constexpr size_t O_A_STA   = O_RGB_ALL + RGB_SZ;
constexpr size_t O_A_DYN   = O_A_STA + A_SZ;
constexpr size_t O_A_ALL   = O_A_DYN + A_SZ;
constexpr size_t O_SEM     = O_A_ALL + A_SZ;
constexpr size_t O_SM      = O_SEM + A_SZ;
constexpr size_t O_TR      = O_SM + 1;

// workspace layout (bytes), total ~4.2 MB
constexpr size_t WS_CNTR  = 512;   // entCnt @+0, sigmaSum[6] @+16, cnt[6] @+48
constexpr size_t WS_TCNT  = 1024;                                    // int[kNBins]
constexpr size_t WS_TTOUCH= WS_TCNT + (size_t)kNBins * 4;            // int[kNBins]
constexpr size_t WS_TLIST = WS_TTOUCH + (size_t)kNBins * 4;          // u16[kNBins*kCAP]
constexpr size_t WS_PAY   = WS_TLIST + (size_t)kNBins * kCAP * 2;    // f32[12*kMaxEnt]

__device__ __forceinline__ float clip01(float x) { return fminf(fmaxf(x, 0.f), 1.f); }
__device__ __forceinline__ unsigned long long packkey(int zbits, int ikey) {
    return ((unsigned long long)(unsigned)zbits << 32) | (unsigned)ikey;
}
__device__ __forceinline__ float packh2(float a, float b) {
    __half2 h = __floats2half2_rn(a, b);
    return __uint_as_float(*reinterpret_cast<unsigned*>(&h));
}
__device__ __forceinline__ float2 unpackh2(float f) {
    unsigned u = __float_as_uint(f);
    return __half22float2(*reinterpret_cast<__half2*>(&u));
}
}

// ---------------- kernels ----------------

// project, emit payloads, append entry ids into per-tile bins; 4x4 inverse inlined
__global__ void k_pre(const float* __restrict__ centers, const float* __restrict__ scale,
                      const float* __restrict__ feat, const float* __restrict__ opac,
                      const float* __restrict__ bgp, const float* __restrict__ intr,
                      const float* __restrict__ fpose, const float* __restrict__ c2w,
                      int* __restrict__ entCnt, float* __restrict__ sigmaSum, int* __restrict__ cnt,
                      int* __restrict__ tileCnt, unsigned short* __restrict__ tileList,
                      float* __restrict__ pay) {
    __shared__ float sW[16];
    int inst = blockIdx.y;
    if (threadIdx.x == 0) {   // Gauss-Jordan inverse of c2w[inst]
        float m[4][8];
        const float* A = c2w + (size_t)inst * 16;
        for (int r = 0; r < 4; ++r)
            for (int cc = 0; cc < 4; ++cc) { m[r][cc] = A[r * 4 + cc]; m[r][cc + 4] = (r == cc) ? 1.f : 0.f; }
        for (int col = 0; col < 4; ++col) {
            int piv = col; float mx = fabsf(m[col][col]);
            for (int r = col + 1; r < 4; ++r) { float a = fabsf(m[r][col]); if (a > mx) { mx = a; piv = r; } }
            if (piv != col)
                for (int cc = 0; cc < 8; ++cc) { float tt = m[col][cc]; m[col][cc] = m[piv][cc]; m[piv][cc] = tt; }
            float inv = 1.f / m[col][col];
            for (int cc = 0; cc < 8; ++cc) m[col][cc] *= inv;
            for (int r = 0; r < 4; ++r) {
                if (r == col) continue;
                float f = m[r][col];
                for (int cc = 0; cc < 8; ++cc) m[r][cc] -= f * m[col][cc];
            }
        }
        for (int r = 0; r < 4; ++r)
            for (int cc = 0; cc < 4; ++cc) sW[r * 4 + cc] = m[r][cc + 4];
    }
    __syncthreads();

    int g = blockIdx.x * 256 + threadIdx.x;   // grid exact: 6144 = 24*256
    int bt = inst / kV, v = inst % kV;
    int b = bt / kT;

    const float* c = centers + ((size_t)bt * kNG + g) * 3;
    float c0 = c[0], c1 = c[1], c2 = c[2];
    const float* P = fpose + (size_t)b * 16;
    float wx[4];
#pragma unroll
    for (int i = 0; i < 4; ++i)
        wx[i] = P[i * 4 + 0] * c0 + P[i * 4 + 1] * c1 + P[i * 4 + 2] * c2 + P[i * 4 + 3];

    float camx = sW[0] * wx[0] + sW[1] * wx[1] + sW[2] * wx[2] + sW[3] * wx[3];
    float camy = sW[4] * wx[0] + sW[5] * wx[1] + sW[6] * wx[2] + sW[7] * wx[3];
    float camz = sW[8] * wx[0] + sW[9] * wx[1] + sW[10] * wx[2] + sW[11] * wx[3];

    float op = clip01(opac[(size_t)bt * kNG + g]);
    bool zok = (camz > 0.001f) && isfinite(camx) && isfinite(camy) && isfinite(camz);
    bool valid0 = zok && (op > 1e-5f);

    const float* it = intr + ((size_t)b * kV + v) * 4;
    float fx = it[0], fy = it[1], cx = it[2], cy = it[3];
    float u = camx * fx / camz + cx;
    float vv = camy * fy / camz + cy;

    const float* sp = scale + ((size_t)bt * kNG + g) * 3;
    float sf = (sp[0] + sp[1] + sp[2]) / 3.f;
    float sg = fminf(fmaxf((fx + fy) * 0.5f * fabsf(sf) / fmaxf(camz, 0.001f), 0.75f), 10.f);

    bool inb = (u >= -3.f) && (u <= (float)kW + 2.f) && (vv >= -3.f) && (vv <= (float)kH + 2.f);
    bool statsValid = valid0 && inb;

    // wave-reduced sigma/cnt stats (1 atomic pair per wave)
    float ssum = statsValid ? sg : 0.f;
    int scnt = statsValid ? 1 : 0;
#pragma unroll
    for (int o = 32; o > 0; o >>= 1) {
        ssum += __shfl_down(ssum, o);
        scnt += __shfl_down(scnt, o);
    }
    if ((threadIdx.x & 63) == 0 && scnt > 0) {
        atomicAdd(&sigmaSum[inst], ssum);
        atomicAdd(&cnt[inst], scnt);
    }

    int x0 = (int)floorf(u);
    int y0 = (int)floorf(vv);
    bool emit = statsValid && (x0 >= -2) && (x0 <= kW + 1) && (y0 >= -2) && (y0 <= kH + 1);
    if (!emit) return;

    float bg = bgp[(size_t)bt * kNG + g];
    float dyn = clip01(1.f - bg);
    float aAll = op;
    float aDyn = clip01(op * dyn);
    float aSta = clip01(op * (1.f - dyn));
    if (aDyn <= 1e-5f) aDyn = 0.f;
    if (aSta <= 1e-5f) aSta = 0.f;

    const float* fc = feat + ((size_t)bt * kNG + g) * 3;
    float r = clip01(fc[0]), gc = clip01(fc[1]), bcl = clip01(fc[2]);

    int e = atomicAdd(entCnt, 1);
    float4* p4 = (float4*)(pay + (size_t)e * 12);
    int keybits = (g << 16) | e;
    p4[0] = make_float4(u, vv, 1.f / fmaxf(sg, 0.001f), aSta);
    p4[1] = make_float4(aDyn, aAll, r, gc);
    p4[2] = make_float4(bcl, camz, __int_as_float(keybits), 0.f);

    // overlapping 64x4 tiles of the footprint [x0-2,x0+2]x[y0-2,y0+2]
    int ilo = x0 - 2 < 0 ? 0 : (x0 - 2) / kTX;
    int ihi = min(kTilesX - 1, (x0 + 2) / kTX);
    int jlo = y0 - 2 < 0 ? 0 : (y0 - 2) / kTY;
    int jhi = min(kTilesY - 1, (y0 + 2) / kTY);
    for (int j = jlo; j <= jhi; ++j)
        for (int i = ilo; i <= ihi; ++i) {
            int bin = inst * kNTiles + j * kTilesX + i;
            int idx = atomicAdd(&tileCnt[bin], 1);
            if (idx < kCAP) tileList[(size_t)bin * kCAP + idx] = (unsigned short)e;
        }
}

// tiled rasterizer: gather own bin, rank-sort by (z,g), pipelined branch-free composite.
// Wave = one 64-px row -> 256B-aligned contiguous stores per plane.
__global__ __launch_bounds__(256) void k_tile(const int* __restrict__ tileCnt,
                                              const unsigned short* __restrict__ tileList,
                                              const float* __restrict__ pay,
                                              float* __restrict__ out,
                                              int* __restrict__ tileTouch) {
    __shared__ unsigned long long shKey[kCAP];
    __shared__ float4 shA[kCAP + 8];
    __shared__ float2 shB[kCAP + 8];
    __shared__ int shT[4];

    int t = threadIdx.x;
    int tile = blockIdx.x;
    int inst = blockIdx.y;
    int bin = inst * kNTiles + tile;
    int N = tileCnt[bin];
    if (N > kCAP) N = kCAP;

    // gather 2 slots per thread (kCAP = 2*256); records in registers until rank known
    unsigned long long kA = ~0ULL, kB = ~0ULL;
    float4 aA, aB; float2 bA, bB;
#define GATHER(i, kq, aq, bq)                                              \
    {   if (i < N) {                                                       \
            int e = tileList[(size_t)bin * kCAP + i];                      \
            const float4* pp = (const float4*)(pay + (size_t)e * 12);      \
            float4 p0 = pp[0], p1 = pp[1], p2 = pp[2];                     \
            kq = packkey(__float_as_int(p2.y), __float_as_int(p2.z));      \
            shKey[i] = kq;                                                 \
            aq = make_float4(p0.x, p0.y, p0.z, packh2(p0.w, p1.x));        \
            bq = make_float2(packh2(p1.y, p1.z), packh2(p1.w, p2.x));      \
        } }
    GATHER(t, kA, aA, bA)
    GATHER(t + 256, kB, aB, bB)
#undef GATHER
    __syncthreads();

    // rank sort (keys unique: low bits hold entry id)
    int rA = 0, rB = 0;
    for (int j = 0; j < N; ++j) {
        unsigned long long kj = shKey[j];
        rA += (kj < kA); rB += (kj < kB);
    }
    __syncthreads();
    if (t < N)       { shA[rA] = aA; shB[rA] = bA; }
    if (t + 256 < N) { shA[rB] = aB; shB[rB] = bB; }
    if (t < 8) {   // zero padding slots for the prefetch pipeline (no-op records)
        shA[N + t] = make_float4(0.f, 0.f, 0.f, 0.f);
        shB[N + t] = make_float2(0.f, 0.f);
    }
    __syncthreads();

    // composite: one pixel per thread; wave w handles row ty+w, lanes = px
    int tx = (tile % kTilesX) * kTX;
    int ty = (tile / kTilesX) * kTY;
    int px = tx + (t & (kTX - 1));
    int py = ty + (t >> 6);
    float fpx = (float)px, fpy = (float)py;

    float ad0 = 0.f, ad1 = 0.f, ad2 = 0.f;
    float sr0 = 0.f, sg0 = 0.f, sb0 = 0.f;
    float sr1 = 0.f, sg1 = 0.f, sb1 = 0.f;
    float sr2 = 0.f, sg2 = 0.f, sb2 = 0.f;

    float4 Ac = shA[0]; float2 Bc = shB[0];
    for (int k = 0; k < N; ++k) {
        float4 An = shA[k + 1]; float2 Bn = shB[k + 1];   // prefetch next (pad-safe)
        {
            float dxc = fpx - floorf(Ac.x);
            float dyc = fpy - floorf(Ac.y);
            bool keep = (dxc >= -2.f) && (dxc <= 2.f) && (dyc >= -2.f) && (dyc <= 2.f);
            float du = (Ac.x - fpx) * Ac.z;
            float dv = (Ac.y - fpy) * Ac.z;
            float lb = expf(-0.5f * (du * du + dv * dv));
            lb = keep ? lb : 0.f;
            float2 sd = unpackh2(Ac.w);   // aSta, aDyn
            float2 ar = unpackh2(Bc.x);   // aAll, r
            float2 gb = unpackh2(Bc.y);   // g, b
            float la, Tt, ct;
            la = fminf(lb * sd.x, 0.999f);
            Tt = clip01(1.f - ad0); ct = la * Tt;
            ad0 = fminf(ad0 + ct, 0.999f);
            sr0 += ar.y * ct; sg0 += gb.x * ct; sb0 += gb.y * ct;
            la = fminf(lb * sd.y, 0.999f);
            Tt = clip01(1.f - ad1); ct = la * Tt;
            ad1 = fminf(ad1 + ct, 0.999f);
            sr1 += ar.y * ct; sg1 += gb.x * ct; sb1 += gb.y * ct;
            la = fminf(lb * ar.x, 0.999f);
            Tt = clip01(1.f - ad2); ct = la * Tt;
            ad2 = fminf(ad2 + ct, 0.999f);
            sr2 += ar.y * ct; sg2 += gb.x * ct; sb2 += gb.y * ct;
        }
        Ac = An; Bc = Bn;
    }

    // touch: per-wave ballot -> LDS -> one contention-free store per WG
    unsigned long long tm = __ballot(ad2 > 1e-6f);
    if ((t & 63) == 0) shT[t >> 6] = __popcll(tm);
    __syncthreads();
    if (t == 0) tileTouch[bin] = shT[0] + shT[1] + shT[2] + shT[3];

    size_t o = (size_t)py * kW + px;
    size_t ib3 = (size_t)inst * 3;
    out[O_RGB_STA + (ib3 + 0) * kHW + o] = clip01(sr0);
    out[O_RGB_STA + (ib3 + 1) * kHW + o] = clip01(sg0);
    out[O_RGB_STA + (ib3 + 2) * kHW + o] = clip01(sb0);
    out[O_RGB_DYN + (ib3 + 0) * kHW + o] = clip01(sr1);
    out[O_RGB_DYN + (ib3 + 1) * kHW + o] = clip01(sg1);
    out[O_RGB_DYN + (ib3 + 2) * kHW + o] = clip01(sb1);
    out[O_RGB_ALL + (ib3 + 0) * kHW + o] = clip01(sr2);
    out[O_RGB_ALL + (ib3 + 1) * kHW + o] = clip01(sg2);
    out[O_RGB_ALL + (ib3 + 2) * kHW + o] = clip01(sb2);
    out[O_A_STA + (size_t)inst * kHW + o] = ad0;
    out[O_A_DYN + (size_t)inst * kHW + o] = ad1;
    out[O_A_ALL + (size_t)inst * kHW + o] = ad2;
}

// 64-thread finalize: parallel reduce of per-bin touch counts + sigma means
__global__ __launch_bounds__(64) void k_fin(const float* __restrict__ sigmaSum,
                                            const int* __restrict__ cnt,
                                            const int* __restrict__ tileTouch,
                                            float* __restrict__ out) {
    int lane = threadIdx.x;
    float sm = 0.f, tr = 0.f;
    for (int inst = 0; inst < kNI; ++inst) {
        int s = 0;
        for (int i = lane; i < kNTiles; i += 64) s += tileTouch[inst * kNTiles + i];
#pragma unroll
        for (int o = 32; o > 0; o >>= 1) s += __shfl_down(s, o);
        if (lane == 0) {
            sm += sigmaSum[inst] / fmaxf((float)cnt[inst], 1.f);
            tr += (float)s / (float)kHW;
        }
    }
    if (lane == 0) {
        out[O_SM] = sm / (float)kNI;
        out[O_TR] = tr / (float)kNI;
    }
}

// ---------------- launch ----------------
extern "C" void kernel_launch(void* const* d_in, const int* in_sizes, int n_in,
                              void* d_out, int out_size, void* d_ws, size_t ws_size,
                              hipStream_t stream) {
    const float* centers = (const float*)d_in[0];
    const float* scal    = (const float*)d_in[1];
    const float* feat    = (const float*)d_in[2];
    const float* opac    = (const float*)d_in[3];
    const float* bgp     = (const float*)d_in[4];
    const float* sem     = (const float*)d_in[5];
    const float* intr    = (const float*)d_in[6];
    const float* c2w     = (const float*)d_in[7];
    const float* fpose   = (const float*)d_in[8];
    float* out = (float*)d_out;
    char* ws = (char*)d_ws;

    int*   entCnt   = (int*)(ws + WS_CNTR);
    float* sigmaSum = (float*)(ws + WS_CNTR + 16);
    int*   cnt      = (int*)(ws + WS_CNTR + 48);
    int*   tileCnt  = (int*)(ws + WS_TCNT);
    int*   tileTouch= (int*)(ws + WS_TTOUCH);
    unsigned short* tileList = (unsigned short*)(ws + WS_TLIST);
    float* pay      = (float*)(ws + WS_PAY);

    // zero counters + tile counts (+touch staging)
    hipMemsetAsync(ws + WS_CNTR, 0, WS_TLIST - WS_CNTR, stream);

    dim3 gpre(kNG / 256, kNI);
    k_pre<<<gpre, 256, 0, stream>>>(centers, scal, feat, opac, bgp, intr, fpose, c2w,
                                    entCnt, sigmaSum, cnt, tileCnt, tileList, pay);

    dim3 gtile(kNTiles, kNI);
    k_tile<<<gtile, 256, 0, stream>>>(tileCnt, tileList, pay, out, tileTouch);

    hipMemcpyAsync(out + O_SEM, sem, (size_t)kNI * kHW * sizeof(float),
                   hipMemcpyDeviceToDevice, stream);

    k_fin<<<1, 64, 0, stream>>>(sigmaSum, cnt, tileTouch, out);
}

// Round 10
// 83.754 us; speedup vs baseline: 4.2363x; 1.0160x over previous
//
#include <hip/hip_runtime.h>
#include <hip/hip_bf16.h>
#include <hip/hip_fp16.h>

// ---------------- problem constants ----------------
namespace {
constexpr int kB = 1, kT = 2, kV = 3;
constexpr int kGH = 32, kGW = 64;
constexpr int kNG = kV * kGH * kGW;      // 6144 gaussians per (b,t)
constexpr int kNBT = kB * kT;            // 2
constexpr int kNI = kNBT * kV;           // 6 render instances
constexpr int kH = 224, kW = 448;
constexpr int kHW = kH * kW;             // 100352

// tile rasterizer: 64x4 pixels per 256-thread WG, 5x5 footprint.
// Each wave = one 64-px row -> every per-plane store = 256B contiguous, 256B-aligned.
constexpr int kTX = 64, kTY = 4;
constexpr int kTilesX = kW / kTX;        // 7
constexpr int kTilesY = kH / kTY;        // 56
constexpr int kNTiles = kTilesX * kTilesY; // 392
constexpr int kNBins = kNI * kNTiles;    // 2352
constexpr int kCAP = 512;                // per-tile capacity (never hit: r9 verified)
constexpr int kMaxEnt = kNI * kNG;       // 36864 (< 65536 -> u16 ids)

// output bases (floats)
constexpr size_t RGB_SZ = (size_t)kNI * 3 * kHW;
constexpr size_t A_SZ   = (size_t)kNI * kHW;
constexpr size_t O_RGB_STA = 0;
constexpr size_t O_RGB_DYN = O_RGB_STA + RGB_SZ;
constexpr size_t O_RGB_ALL = O_RGB_DYN + RGB_SZ;
constexpr size_t O_A_STA   = O_RGB_ALL + RGB_SZ;
constexpr size_t O_A_DYN   = O_A_STA + A_SZ;
constexpr size_t O_A_ALL   = O_A_DYN + A_SZ;
constexpr size_t O_SEM     = O_A_ALL + A_SZ;
constexpr size_t O_SM      = O_SEM + A_SZ;
constexpr size_t O_TR      = O_SM + 1;

// workspace layout (bytes), total ~4.2 MB
constexpr size_t WS_CNTR  = 512;   // entCnt @+0, sigmaSum[6] @+16, cnt[6] @+48
constexpr size_t WS_TCNT  = 1024;                                    // int[kNBins]
constexpr size_t WS_TTOUCH= WS_TCNT + (size_t)kNBins * 4;            // int[kNBins] (no zeroing needed)
constexpr size_t WS_TLIST = WS_TTOUCH + (size_t)kNBins * 4;          // u16[kNBins*kCAP]
constexpr size_t WS_PAY   = WS_TLIST + (size_t)kNBins * kCAP * 2;    // f32[12*kMaxEnt]

// zero range: [WS_CNTR, WS_TCNT + kNBins*4) = [512, 10432) = 2480 ints
constexpr int kZeroInts = (int)((WS_TCNT + (size_t)kNBins * 4 - WS_CNTR) / 4);

__device__ __forceinline__ float clip01(float x) { return fminf(fmaxf(x, 0.f), 1.f); }
__device__ __forceinline__ unsigned long long packkey(int zbits, int ikey) {
    return ((unsigned long long)(unsigned)zbits << 32) | (unsigned)ikey;
}
__device__ __forceinline__ float packh2(float a, float b) {
    __half2 h = __floats2half2_rn(a, b);
    return __uint_as_float(*reinterpret_cast<unsigned*>(&h));
}
__device__ __forceinline__ float2 unpackh2(float f) {
    unsigned u = __float_as_uint(f);
    return __half22float2(*reinterpret_cast<__half2*>(&u));
}
}

// ---------------- kernels ----------------

// zero counters + tileCnt (replaces rocclr fillBuffer, which showed ~42us fixed cost)
__global__ __launch_bounds__(256) void k_zero(int* __restrict__ p) {
    int i = blockIdx.x * 256 + threadIdx.x;
    if (i < kZeroInts) p[i] = 0;
}

// project, emit payloads, append entry ids into per-tile bins; 4x4 inverse inlined
__global__ void k_pre(const float* __restrict__ centers, const float* __restrict__ scale,
                      const float* __restrict__ feat, const float* __restrict__ opac,
                      const float* __restrict__ bgp, const float* __restrict__ intr,
                      const float* __restrict__ fpose, const float* __restrict__ c2w,
                      int* __restrict__ entCnt, float* __restrict__ sigmaSum, int* __restrict__ cnt,
                      int* __restrict__ tileCnt, unsigned short* __restrict__ tileList,
                      float* __restrict__ pay) {
    __shared__ float sW[16];
    int inst = blockIdx.y;
    if (threadIdx.x == 0) {   // Gauss-Jordan inverse of c2w[inst]
        float m[4][8];
        const float* A = c2w + (size_t)inst * 16;
        for (int r = 0; r < 4; ++r)
            for (int cc = 0; cc < 4; ++cc) { m[r][cc] = A[r * 4 + cc]; m[r][cc + 4] = (r == cc) ? 1.f : 0.f; }
        for (int col = 0; col < 4; ++col) {
            int piv = col; float mx = fabsf(m[col][col]);
            for (int r = col + 1; r < 4; ++r) { float a = fabsf(m[r][col]); if (a > mx) { mx = a; piv = r; } }
            if (piv != col)
                for (int cc = 0; cc < 8; ++cc) { float tt = m[col][cc]; m[col][cc] = m[piv][cc]; m[piv][cc] = tt; }
            float inv = 1.f / m[col][col];
            for (int cc = 0; cc < 8; ++cc) m[col][cc] *= inv;
            for (int r = 0; r < 4; ++r) {
                if (r == col) continue;
                float f = m[r][col];
                for (int cc = 0; cc < 8; ++cc) m[r][cc] -= f * m[col][cc];
            }
        }
        for (int r = 0; r < 4; ++r)
            for (int cc = 0; cc < 4; ++cc) sW[r * 4 + cc] = m[r][cc + 4];
    }
    __syncthreads();

    int g = blockIdx.x * 256 + threadIdx.x;   // grid exact: 6144 = 24*256
    int bt = inst / kV, v = inst % kV;
    int b = bt / kT;

    const float* c = centers + ((size_t)bt * kNG + g) * 3;
    float c0 = c[0], c1 = c[1], c2 = c[2];
    const float* P = fpose + (size_t)b * 16;
    float wx[4];
#pragma unroll
    for (int i = 0; i < 4; ++i)
        wx[i] = P[i * 4 + 0] * c0 + P[i * 4 + 1] * c1 + P[i * 4 + 2] * c2 + P[i * 4 + 3];

    float camx = sW[0] * wx[0] + sW[1] * wx[1] + sW[2] * wx[2] + sW[3] * wx[3];
    float camy = sW[4] * wx[0] + sW[5] * wx[1] + sW[6] * wx[2] + sW[7] * wx[3];
    float camz = sW[8] * wx[0] + sW[9] * wx[1] + sW[10] * wx[2] + sW[11] * wx[3];

    float op = clip01(opac[(size_t)bt * kNG + g]);
    bool zok = (camz > 0.001f) && isfinite(camx) && isfinite(camy) && isfinite(camz);
    bool valid0 = zok && (op > 1e-5f);

    const float* it = intr + ((size_t)b * kV + v) * 4;
    float fx = it[0], fy = it[1], cx = it[2], cy = it[3];
    float u = camx * fx / camz + cx;
    float vv = camy * fy / camz + cy;

    const float* sp = scale + ((size_t)bt * kNG + g) * 3;
    float sf = (sp[0] + sp[1] + sp[2]) / 3.f;
    float sg = fminf(fmaxf((fx + fy) * 0.5f * fabsf(sf) / fmaxf(camz, 0.001f), 0.75f), 10.f);

    bool inb = (u >= -3.f) && (u <= (float)kW + 2.f) && (vv >= -3.f) && (vv <= (float)kH + 2.f);
    bool statsValid = valid0 && inb;

    // wave-reduced sigma/cnt stats (1 atomic pair per wave)
    float ssum = statsValid ? sg : 0.f;
    int scnt = statsValid ? 1 : 0;
#pragma unroll
    for (int o = 32; o > 0; o >>= 1) {
        ssum += __shfl_down(ssum, o);
        scnt += __shfl_down(scnt, o);
    }
    if ((threadIdx.x & 63) == 0 && scnt > 0) {
        atomicAdd(&sigmaSum[inst], ssum);
        atomicAdd(&cnt[inst], scnt);
    }

    int x0 = (int)floorf(u);
    int y0 = (int)floorf(vv);
    bool emit = statsValid && (x0 >= -2) && (x0 <= kW + 1) && (y0 >= -2) && (y0 <= kH + 1);
    if (!emit) return;

    float bg = bgp[(size_t)bt * kNG + g];
    float dyn = clip01(1.f - bg);
    float aAll = op;
    float aDyn = clip01(op * dyn);
    float aSta = clip01(op * (1.f - dyn));
    if (aDyn <= 1e-5f) aDyn = 0.f;
    if (aSta <= 1e-5f) aSta = 0.f;

    const float* fc = feat + ((size_t)bt * kNG + g) * 3;
    float r = clip01(fc[0]), gc = clip01(fc[1]), bcl = clip01(fc[2]);

    int e = atomicAdd(entCnt, 1);
    float4* p4 = (float4*)(pay + (size_t)e * 12);
    int keybits = (g << 16) | e;
    p4[0] = make_float4(u, vv, 1.f / fmaxf(sg, 0.001f), aSta);
    p4[1] = make_float4(aDyn, aAll, r, gc);
    p4[2] = make_float4(bcl, camz, __int_as_float(keybits), 0.f);

    // overlapping 64x4 tiles of the footprint [x0-2,x0+2]x[y0-2,y0+2]
    int ilo = x0 - 2 < 0 ? 0 : (x0 - 2) / kTX;
    int ihi = min(kTilesX - 1, (x0 + 2) / kTX);
    int jlo = y0 - 2 < 0 ? 0 : (y0 - 2) / kTY;
    int jhi = min(kTilesY - 1, (y0 + 2) / kTY);
    for (int j = jlo; j <= jhi; ++j)
        for (int i = ilo; i <= ihi; ++i) {
            int bin = inst * kNTiles + j * kTilesX + i;
            int idx = atomicAdd(&tileCnt[bin], 1);
            if (idx < kCAP) tileList[(size_t)bin * kCAP + idx] = (unsigned short)e;
        }
}

// tiled rasterizer: gather own bin, rank-sort by (z,g), pipelined branch-free composite.
// Wave = one 64-px row -> 256B-aligned contiguous stores per plane. Sem passthrough folded in.
__global__ __launch_bounds__(256) void k_tile(const int* __restrict__ tileCnt,
                                              const unsigned short* __restrict__ tileList,
                                              const float* __restrict__ pay,
                                              const float* __restrict__ sem,
                                              float* __restrict__ out,
                                              int* __restrict__ tileTouch) {
    __shared__ unsigned long long shKey[kCAP];
    __shared__ float4 shA[kCAP + 8];
    __shared__ float2 shB[kCAP + 8];
    __shared__ int shT[4];

    int t = threadIdx.x;
    int tile = blockIdx.x;
    int inst = blockIdx.y;
    int bin = inst * kNTiles + tile;
    int N = tileCnt[bin];
    if (N > kCAP) N = kCAP;

    // gather 2 slots per thread (kCAP = 2*256); records in registers until rank known
    unsigned long long kA = ~0ULL, kB = ~0ULL;
    float4 aA, aB; float2 bA, bB;
#define GATHER(i, kq, aq, bq)                                              \
    {   if (i < N) {                                                       \
            int e = tileList[(size_t)bin * kCAP + i];                      \
            const float4* pp = (const float4*)(pay + (size_t)e * 12);      \
            float4 p0 = pp[0], p1 = pp[1], p2 = pp[2];                     \
            kq = packkey(__float_as_int(p2.y), __float_as_int(p2.z));      \
            shKey[i] = kq;                                                 \
            aq = make_float4(p0.x, p0.y, p0.z, packh2(p0.w, p1.x));        \
            bq = make_float2(packh2(p1.y, p1.z), packh2(p1.w, p2.x));      \
        } }
    GATHER(t, kA, aA, bA)
    GATHER(t + 256, kB, aB, bB)
#undef GATHER
    __syncthreads();

    // rank sort (keys unique: low bits hold entry id)
    int rA = 0, rB = 0;
    for (int j = 0; j < N; ++j) {
        unsigned long long kj = shKey[j];
        rA += (kj < kA); rB += (kj < kB);
    }
    __syncthreads();
    if (t < N)       { shA[rA] = aA; shB[rA] = bA; }
    if (t + 256 < N) { shA[rB] = aB; shB[rB] = bB; }
    if (t < 8) {   // zero padding slots for the prefetch pipeline (no-op records)
        shA[N + t] = make_float4(0.f, 0.f, 0.f, 0.f);
        shB[N + t] = make_float2(0.f, 0.f);
    }
    __syncthreads();

    // composite: one pixel per thread; wave w handles row ty+w, lanes = px
    int tx = (tile % kTilesX) * kTX;
    int ty = (tile / kTilesX) * kTY;
    int px = tx + (t & (kTX - 1));
    int py = ty + (t >> 6);
    float fpx = (float)px, fpy = (float)py;

    float ad0 = 0.f, ad1 = 0.f, ad2 = 0.f;
    float sr0 = 0.f, sg0 = 0.f, sb0 = 0.f;
    float sr1 = 0.f, sg1 = 0.f, sb1 = 0.f;
    float sr2 = 0.f, sg2 = 0.f, sb2 = 0.f;

    float4 Ac = shA[0]; float2 Bc = shB[0];
    for (int k = 0; k < N; ++k) {
        float4 An = shA[k + 1]; float2 Bn = shB[k + 1];   // prefetch next (pad-safe)
        {
            float dxc = fpx - floorf(Ac.x);
            float dyc = fpy - floorf(Ac.y);
            bool keep = (dxc >= -2.f) && (dxc <= 2.f) && (dyc >= -2.f) && (dyc <= 2.f);
            float du = (Ac.x - fpx) * Ac.z;
            float dv = (Ac.y - fpy) * Ac.z;
            float lb = expf(-0.5f * (du * du + dv * dv));
            lb = keep ? lb : 0.f;
            float2 sd = unpackh2(Ac.w);   // aSta, aDyn
            float2 ar = unpackh2(Bc.x);   // aAll, r
            float2 gb = unpackh2(Bc.y);   // g, b
            float la, Tt, ct;
            la = fminf(lb * sd.x, 0.999f);
            Tt = clip01(1.f - ad0); ct = la * Tt;
            ad0 = fminf(ad0 + ct, 0.999f);
            sr0 += ar.y * ct; sg0 += gb.x * ct; sb0 += gb.y * ct;
            la = fminf(lb * sd.y, 0.999f);
            Tt = clip01(1.f - ad1); ct = la * Tt;
            ad1 = fminf(ad1 + ct, 0.999f);
            sr1 += ar.y * ct; sg1 += gb.x * ct; sb1 += gb.y * ct;
            la = fminf(lb * ar.x, 0.999f);
            Tt = clip01(1.f - ad2); ct = la * Tt;
            ad2 = fminf(ad2 + ct, 0.999f);
            sr2 += ar.y * ct; sg2 += gb.x * ct; sb2 += gb.y * ct;
        }
        Ac = An; Bc = Bn;
    }

    // touch: per-wave ballot -> LDS -> one contention-free store per WG
    unsigned long long tm = __ballot(ad2 > 1e-6f);
    if ((t & 63) == 0) shT[t >> 6] = __popcll(tm);
    __syncthreads();
    if (t == 0) tileTouch[bin] = shT[0] + shT[1] + shT[2] + shT[3];

    size_t o = (size_t)py * kW + px;
    size_t ib3 = (size_t)inst * 3;
    out[O_RGB_STA + (ib3 + 0) * kHW + o] = clip01(sr0);
    out[O_RGB_STA + (ib3 + 1) * kHW + o] = clip01(sg0);
    out[O_RGB_STA + (ib3 + 2) * kHW + o] = clip01(sb0);
    out[O_RGB_DYN + (ib3 + 0) * kHW + o] = clip01(sr1);
    out[O_RGB_DYN + (ib3 + 1) * kHW + o] = clip01(sg1);
    out[O_RGB_DYN + (ib3 + 2) * kHW + o] = clip01(sb1);
    out[O_RGB_ALL + (ib3 + 0) * kHW + o] = clip01(sr2);
    out[O_RGB_ALL + (ib3 + 1) * kHW + o] = clip01(sg2);
    out[O_RGB_ALL + (ib3 + 2) * kHW + o] = clip01(sb2);
    out[O_A_STA + (size_t)inst * kHW + o] = ad0;
    out[O_A_DYN + (size_t)inst * kHW + o] = ad1;
    out[O_A_ALL + (size_t)inst * kHW + o] = ad2;
    out[O_SEM + (size_t)inst * kHW + o] = sem[(size_t)inst * kHW + o];   // folded passthrough
}

// 64-thread finalize: parallel reduce of per-bin touch counts + sigma means
__global__ __launch_bounds__(64) void k_fin(const float* __restrict__ sigmaSum,
                                            const int* __restrict__ cnt,
                                            const int* __restrict__ tileTouch,
                                            float* __restrict__ out) {
    int lane = threadIdx.x;
    float sm = 0.f, tr = 0.f;
    for (int inst = 0; inst < kNI; ++inst) {
        int s = 0;
        for (int i = lane; i < kNTiles; i += 64) s += tileTouch[inst * kNTiles + i];
#pragma unroll
        for (int o = 32; o > 0; o >>= 1) s += __shfl_down(s, o);
        if (lane == 0) {
            sm += sigmaSum[inst] / fmaxf((float)cnt[inst], 1.f);
            tr += (float)s / (float)kHW;
        }
    }
    if (lane == 0) {
        out[O_SM] = sm / (float)kNI;
        out[O_TR] = tr / (float)kNI;
    }
}

// ---------------- launch ----------------
extern "C" void kernel_launch(void* const* d_in, const int* in_sizes, int n_in,
                              void* d_out, int out_size, void* d_ws, size_t ws_size,
                              hipStream_t stream) {
    const float* centers = (const float*)d_in[0];
    const float* scal    = (const float*)d_in[1];
    const float* feat    = (const float*)d_in[2];
    const float* opac    = (const float*)d_in[3];
    const float* bgp     = (const float*)d_in[4];
    const float* sem     = (const float*)d_in[5];
    const float* intr    = (const float*)d_in[6];
    const float* c2w     = (const float*)d_in[7];
    const float* fpose   = (const float*)d_in[8];
    float* out = (float*)d_out;
    char* ws = (char*)d_ws;

    int*   entCnt   = (int*)(ws + WS_CNTR);
    float* sigmaSum = (float*)(ws + WS_CNTR + 16);
    int*   cnt      = (int*)(ws + WS_CNTR + 48);
    int*   tileCnt  = (int*)(ws + WS_TCNT);
    int*   tileTouch= (int*)(ws + WS_TTOUCH);
    unsigned short* tileList = (unsigned short*)(ws + WS_TLIST);
    float* pay      = (float*)(ws + WS_PAY);

    k_zero<<<(kZeroInts + 255) / 256, 256, 0, stream>>>((int*)(ws + WS_CNTR));

    dim3 gpre(kNG / 256, kNI);
    k_pre<<<gpre, 256, 0, stream>>>(centers, scal, feat, opac, bgp, intr, fpose, c2w,
                                    entCnt, sigmaSum, cnt, tileCnt, tileList, pay);

    dim3 gtile(kNTiles, kNI);
    k_tile<<<gtile, 256, 0, stream>>>(tileCnt, tileList, pay, sem, out, tileTouch);

    k_fin<<<1, 64, 0, stream>>>(sigmaSum, cnt, tileTouch, out);
}